// Round 8
// baseline (456.748 us; speedup 1.0000x reference)
//
#include <hip/hip_runtime.h>
#include <math.h>

#define NPERSEG 30
#define STEPW 15
#define NSEG 3
#define NF 16
#define PATCH 60
#define STRIDE 30
#define NP_ROW 199
#define NBATCH 1024
#define T_LEN 6000
#define NPATCH_TOTAL (NBATCH * NP_ROW)   /* 203776 */
#define GB 32
#define NBLK_B (NPATCH_TOTAL / GB)       /* 6368 */

// f64 twiddles cos/sin(2*pi*m/30), correctly-rounded decimal literals.
constexpr double TC[30] = {
  1.0,
  0.97814760073380563793,
  0.91354545764260089550,
  0.80901699437494742410,
  0.66913060635885821383,
  0.5,
  0.30901699437494742410,
  0.10452846326765347140,
 -0.10452846326765347140,
 -0.30901699437494742410,
 -0.5,
 -0.66913060635885821383,
 -0.80901699437494742410,
 -0.91354545764260089550,
 -0.97814760073380563793,
 -1.0,
 -0.97814760073380563793,
 -0.91354545764260089550,
 -0.80901699437494742410,
 -0.66913060635885821383,
 -0.5,
 -0.30901699437494742410,
 -0.10452846326765347140,
  0.10452846326765347140,
  0.30901699437494742410,
  0.5,
  0.66913060635885821383,
  0.80901699437494742410,
  0.91354545764260089550,
  0.97814760073380563793,
};
constexpr double TS[30] = {
  0.0,
  0.20791169081775933710,
  0.40673664307580020775,
  0.58778525229247312917,
  0.74314482547739423501,
  0.86602540378443864676,
  0.95105651629515357212,
  0.99452189536827333692,
  0.99452189536827333692,
  0.95105651629515357212,
  0.86602540378443864676,
  0.74314482547739423501,
  0.58778525229247312917,
  0.40673664307580020775,
  0.20791169081775933710,
  0.0,
 -0.20791169081775933710,
 -0.40673664307580020775,
 -0.58778525229247312917,
 -0.74314482547739423501,
 -0.86602540378443864676,
 -0.95105651629515357212,
 -0.99452189536827333692,
 -0.99452189536827333692,
 -0.95105651629515357212,
 -0.86602540378443864676,
 -0.74314482547739423501,
 -0.58778525229247312917,
 -0.40673664307580020775,
 -0.20791169081775933710,
};
// WIN_NORM = 200 * sum(hann^2) = 2250 exactly (periodic hann, N=30).
constexpr double INV_WN = 1.0 / 2250.0;
constexpr double THIRD  = 1.0 / 3.0;

// numpy's pairwise f32 sum for n=30
__device__ __forceinline__ float np_sum30_f32(const float* a) {
    float r[8];
#pragma unroll
    for (int j = 0; j < 8; ++j) r[j] = a[j];
#pragma unroll
    for (int i = 8; i < 24; i += 8)
#pragma unroll
        for (int j = 0; j < 8; ++j) r[j] += a[i + j];
    float res = ((r[0] + r[1]) + (r[2] + r[3])) + ((r[4] + r[5]) + (r[6] + r[7]));
#pragma unroll
    for (int i = 24; i < 30; ++i) res += a[i];
    return res;
}

// numpy pairwise f64 sum for n=16
__device__ __forceinline__ double np_sum16_f64(const double* a) {
    double r[8];
#pragma unroll
    for (int j = 0; j < 8; ++j) r[j] = a[j] + a[8 + j];
    return ((r[0] + r[1]) + (r[2] + r[3])) + ((r[4] + r[5]) + (r[6] + r[7]));
}

// 8-bin half of the folded Welch DFT. KBASE is compile-time so every twiddle
// folds to a literal. Per-bin chain: re = (y0 +/- y15), then += u[m]*TC
// m-ascending; im += v[m]*TS (nonzero terms only); pw = (re^2+im^2)*INV_WN,
// doubled unless k==0 or k==15; psd[k] = ((s0+s1)+s2)*THIRD. This is EXACTLY
// the round-7 verified per-bin summation order (absmax 0.015625).
template<int KBASE>
__device__ __forceinline__ void dft_half(const float* __restrict__ pf, double* psdh) {
#pragma unroll
    for (int j = 0; j < 8; ++j) psdh[j] = 0.0;
#pragma unroll 1
    for (int s = 0; s < NSEG; ++s) {
        float y[NPERSEG];
        {
            float q[NPERSEG];
#pragma unroll
            for (int n = 0; n < NPERSEG; ++n) q[n] = pf[s * STEPW + n];
            const float res = np_sum30_f32(q);
            const float smean = res / 30.0f;
#pragma unroll
            for (int n = 0; n < NPERSEG; ++n) {
                const float hn = (float)(0.5 * (1.0 - TC[n]));
                y[n] = (q[n] - smean) * hn;
            }
        }
        const double y0d  = (double)y[0];
        const double y15d = (double)y[15];
        double re[8], im[8];
#pragma unroll
        for (int j = 0; j < 8; ++j) {
            re[j] = ((KBASE + j) & 1) ? (y0d - y15d) : (y0d + y15d);
            im[j] = 0.0;
        }
#pragma unroll
        for (int m = 1; m < 15; ++m) {
            const double u = (double)y[m] + (double)y[NPERSEG - m];
            const double v = (double)y[m] - (double)y[NPERSEG - m];
#pragma unroll
            for (int j = 0; j < 8; ++j) {
                const double tcv = TC[((KBASE + j) * m) % 30];
                const double tsv = TS[((KBASE + j) * m) % 30];
                re[j] += u * tcv;
                if (tsv != 0.0) im[j] += v * tsv;   // compile-time skip of zeros
            }
        }
#pragma unroll
        for (int j = 0; j < 8; ++j) {
            double pw = re[j] * re[j] + im[j] * im[j];
            pw *= INV_WN;
            if ((KBASE + j) != 0 && (KBASE + j) != NF - 1) pw = pw + pw;  // ONESIDED
            psdh[j] += pw;
        }
    }
#pragma unroll
    for (int j = 0; j < 8; ++j) psdh[j] *= THIRD;
}

// ===================== Kernel A: per-patch features (f64) =====================
// One block = one row, 512 threads: patch pid is split across a thread PAIR.
// Role A (waves 0-3) computes DFT bins 0-7 + all spectral features; role B
// (waves 4-7) computes bins 8-15 + the whole morph pipeline. B posts its psd
// half through padded LDS before the barrier; after it, B's morph overlaps A's
// spectral. Halves the per-thread serial chain (feat was latency-bound: r6->r7
// FLOP halving didn't move it). All arithmetic verbatim from round 7.
__global__ __launch_bounds__(512) void feat_kernel(
    const float* __restrict__ x,
    const float* __restrict__ g_m, const float* __restrict__ b_m,
    const float* __restrict__ g_s, const float* __restrict__ b_s,
    float* __restrict__ out)
{
    __shared__ float  xs[T_LEN];
    __shared__ double psd1s[NP_ROW][9];   // stride 9 f64 = 72B: avoids 32-way conflict

    const int tid = threadIdx.x;
    const int row = blockIdx.x;

    {
        const float4* src = reinterpret_cast<const float4*>(x + (size_t)row * T_LEN);
        float4* dst = reinterpret_cast<float4*>(xs);
        for (int i = tid; i < T_LEN / 4; i += 512) dst[i] = src[i];
    }
    __syncthreads();

    const int pid  = tid & 255;
    const int role = tid >> 8;            // wave-uniform (waves 0-3 = A, 4-7 = B)
    const bool active = pid < NP_ROW;

    const float* pf = xs + pid * STRIDE;
    const int p = row * NP_ROW + pid;
    float* op = out + (size_t)(p >> 5) * (GB * 256) + (size_t)(p & 31) * 22;

    double psdh[8];
    if (active) {
        if (role == 0) {
            dft_half<0>(pf, psdh);
        } else {
            dft_half<8>(pf, psdh);
#pragma unroll
            for (int j = 0; j < 8; ++j) psd1s[pid][j] = psdh[j];
        }
    }
    __syncthreads();

    if (active && role == 1) {
        // ---- morph: two fused streaming passes (verbatim round 7) ----
        double morph[13];
        {
            const float v0f = pf[0];
            const double v0 = (double)v0f;
            double vmax = v0, vmin = v0, vsum = v0;
            float aval = fabsf(v0f); int amax = 0;
            float sv0 = v0f + 1e-10f;
            int prev = (sv0 > 0.0f) - (sv0 < 0.0f);
            int zc = 0;
            double dmax = 0.0, dmin = 0.0, dabssum = 0.0;
            double vprev = v0;
#pragma unroll
            for (int n = 1; n < PATCH; ++n) {
                const float vf = pf[n];
                const double v = (double)vf;
                vmax = fmax(vmax, v); vmin = fmin(vmin, v); vsum += v;
                const float a = fabsf(vf);
                if (a > aval) { aval = a; amax = n; }
                const float sv = vf + 1e-10f;
                const int sg = (sv > 0.0f) - (sv < 0.0f);
                if (sg != prev) zc++;
                prev = sg;
                const double d = v - vprev;
                if (n == 1) { dmax = d; dmin = d; dabssum = fabs(d); }
                else { dmax = fmax(dmax, d); dmin = fmin(dmin, d); dabssum += fabs(d); }
                vprev = v;
            }
            const double vmean = vsum / 60.0;
            const double dabsmean = dabssum / 59.0;
            const double peak_loc = (double)((float)amax / 60.0f);
            const double zcf = (double)zc / 60.0;

            double s2 = 0.0, s3 = 0.0, s4 = 0.0, ssq = 0.0;
#pragma unroll
            for (int n = 0; n < PATCH; ++n) {
                const double v = (double)pf[n];
                const double c = v - vmean, c2 = c * c;
                s2 += c2; s3 += c2 * c; s4 += c2 * c2;
                ssq += v * v;
            }
            const double m2 = s2 / 60.0, m3 = s3 / 60.0, m4 = s4 / 60.0;
            const double vstd = sqrt(m2);
            const double kurt = m4 / (m2 * m2) - 3.0;
            const double skew = m3 / (m2 * sqrt(m2));

            morph[0] = vmax;  morph[1] = vmin;  morph[2] = vmax - vmin;
            morph[3] = vmean; morph[4] = vstd;  morph[5] = peak_loc;
            morph[6] = dmax;  morph[7] = dmin;  morph[8] = dabsmean;
            morph[9] = zcf;   morph[10] = ssq;  morph[11] = kurt; morph[12] = skew;
#pragma unroll
            for (int i = 0; i < 13; ++i) if (!isfinite(morph[i])) morph[i] = 0.0;
        }
        // morph group layernorm (f64) -> f[0..12]
        {
            double mu = 0.0;
#pragma unroll
            for (int i = 0; i < 13; ++i) mu += morph[i];
            mu /= 13.0;
            double var = 0.0;
#pragma unroll
            for (int i = 0; i < 13; ++i) { double d = morph[i] - mu; var += d * d; }
            var /= 13.0;
            const double inv = 1.0 / sqrt(var + 1e-5);
            float fm[13];
#pragma unroll
            for (int i = 0; i < 13; ++i)
                fm[i] = (float)((morph[i] - mu) * inv * (double)g_m[i] + (double)b_m[i]);
#pragma unroll
            for (int i = 0; i < 6; ++i)
                *reinterpret_cast<float2*>(op + 2 * i) = make_float2(fm[2 * i], fm[2 * i + 1]);
            op[12] = fm[12];
        }
    }

    if (active && role == 0) {
        // assemble full psd: half 0 from regs, half 1 from LDS (same f64 bits)
        double psd[NF];
#pragma unroll
        for (int j = 0; j < 8; ++j) psd[j] = psdh[j];
#pragma unroll
        for (int j = 0; j < 8; ++j) psd[8 + j] = psd1s[pid][j];

        // ---- spectral features, f64 (verbatim round 7) ----
        const double total = np_sum16_f64(psd) + 1e-12;
        const double invt = 1.0 / total;

        const double band1 = psd[1] * invt;
        const double band3 = ((psd[2] + psd[3]) + psd[4]) * invt;
        double b4s = 0.0;
#pragma unroll
        for (int k = 5; k <= 14; ++k) b4s += psd[k];
        const double band4 = b4s * invt;

        int bk = 0; double bpv = psd[0];
#pragma unroll
        for (int k = 1; k < NF; ++k) if (psd[k] > bpv) { bpv = psd[k]; bk = k; }

        const double th = 0.95 * total;
        int ek = 0;
        {
            double acc = 0.0; bool found = false;
#pragma unroll
            for (int k = 0; k < NF; ++k) {
                acc += psd[k];
                if (!found && acc >= th) { ek = k; found = true; }
            }
        }

        double ent = 0.0;
#pragma unroll
        for (int k = 0; k < NF; ++k) {
            const double pn = psd[k] * invt;
            ent -= pn * log2(pn + 1e-12);
        }

        double spec[9];
        spec[0] = 0.0;
        spec[1] = band1;
        spec[2] = 0.0;
        spec[3] = band3;
        spec[4] = band4;
        spec[5] = (double)((float)((double)bk * 200.0 / 30.0));
        spec[6] = (double)((float)((double)ek * 200.0 / 30.0));
        spec[7] = ent;
        spec[8] = total;
#pragma unroll
        for (int i = 0; i < 9; ++i) if (!isfinite(spec[i])) spec[i] = 0.0;

        // spec group layernorm (f64) -> f[13..21]
        {
            double mu = 0.0;
#pragma unroll
            for (int i = 0; i < 9; ++i) mu += spec[i];
            mu /= 9.0;
            double var = 0.0;
#pragma unroll
            for (int i = 0; i < 9; ++i) { double d = spec[i] - mu; var += d * d; }
            var /= 9.0;
            const double inv = 1.0 / sqrt(var + 1e-5);
            float fs[9];
#pragma unroll
            for (int i = 0; i < 9; ++i)
                fs[i] = (float)((spec[i] - mu) * inv * (double)g_s[i] + (double)b_s[i]);
            op[13] = fs[0];
#pragma unroll
            for (int i = 0; i < 4; ++i)
                *reinterpret_cast<float2*>(op + 14 + 2 * i) = make_float2(fs[1 + 2 * i], fs[2 + 2 * i]);
        }
    }
}

// ===================== Kernel B: MLP (f32) =====================
// Round-5 verified structure. (256,6): VGPR cap ~84 >= the ~56 this kernel
// naturally uses (r5), so no AGPR round-trips (r7 at (256,8) reported VGPR=32 —
// impossible for acc[8]x4 — the allocator was staging through AGPRs, inflating
// VALU ops), while still getting 6 waves/SIMD (vs r5's 4).
// One block = 32 patches; thread owns 4 consecutive channels x 8 patches; wave
// wv owns patches 8wv..8wv+7 and all 256 ch -> in-wave LN shuffle reduction.
// Per-accumulator k-order unchanged -> W2 GEMM bit-identical to verified.
__global__ __launch_bounds__(256, 6) void mlp_kernel(
    const float* __restrict__ W1, const float* __restrict__ b1,
    const float* __restrict__ W2, const float* __restrict__ b2,
    const float* __restrict__ g_o, const float* __restrict__ b_o,
    float* __restrict__ out)
{
    __shared__ float Fsl[GB * 22];     // 704 floats
    __shared__ float Hs[GB][128];

    const int tid = threadIdx.x;
    const size_t base = (size_t)blockIdx.x * (GB * 256);

    // stage this block's compact feature slab (176 float4 = 704 floats)
    if (tid < 176)
        reinterpret_cast<float4*>(Fsl)[tid] =
            *reinterpret_cast<const float4*>(out + base + 4 * (size_t)tid);
    __syncthreads();

    // ---- W1 + exact gelu -> Hs ----
    {
        const int hc  = tid & 127;
        const int ppb = tid >> 7;
        float w1c[22];
#pragma unroll
        for (int k = 0; k < 22; ++k) w1c[k] = W1[k * 128 + hc];
        const float b1v = b1[hc];
#pragma unroll
        for (int v = 0; v < 16; ++v) {
            const int pp = ppb + 2 * v;
            float a = b1v;
#pragma unroll
            for (int k = 0; k < 22; ++k) a += Fsl[pp * 22 + k] * w1c[k];
            Hs[pp][hc] = 0.5f * a * (1.0f + erff(a * 0.70710678118654752440f));
        }
    }
    __syncthreads();

    // ---- W2 GEMM: thread owns 4 consecutive channels x 8 patches ----
    const int cb = tid & 63;
    const int wv = tid >> 6;

    float4 acc[8];
    {
        const float4 b2v = *reinterpret_cast<const float4*>(b2 + 4 * cb);
#pragma unroll
        for (int p = 0; p < 8; ++p) acc[p] = b2v;
    }

#pragma unroll 2
    for (int k = 0; k < 128; k += 4) {
        float4 w0 = *reinterpret_cast<const float4*>(&W2[(k + 0) * 256 + 4 * cb]);
        float4 w1 = *reinterpret_cast<const float4*>(&W2[(k + 1) * 256 + 4 * cb]);
        float4 w2 = *reinterpret_cast<const float4*>(&W2[(k + 2) * 256 + 4 * cb]);
        float4 w3 = *reinterpret_cast<const float4*>(&W2[(k + 3) * 256 + 4 * cb]);
#pragma unroll
        for (int p = 0; p < 8; ++p) {
            const float4 h = *reinterpret_cast<const float4*>(&Hs[8 * wv + p][k]);
            // k-ascending FMA order per accumulator (bit-identical to verified)
            acc[p].x += h.x * w0.x; acc[p].y += h.x * w0.y;
            acc[p].z += h.x * w0.z; acc[p].w += h.x * w0.w;
            acc[p].x += h.y * w1.x; acc[p].y += h.y * w1.y;
            acc[p].z += h.y * w1.z; acc[p].w += h.y * w1.w;
            acc[p].x += h.z * w2.x; acc[p].y += h.z * w2.y;
            acc[p].z += h.z * w2.z; acc[p].w += h.z * w2.w;
            acc[p].x += h.w * w3.x; acc[p].y += h.w * w3.y;
            acc[p].z += h.w * w3.z; acc[p].w += h.w * w3.w;
        }
    }

    // ---- 256-ch layernorm: in-wave reduction, float4 store ----
    const float4 go4 = *reinterpret_cast<const float4*>(g_o + 4 * cb);
    const float4 bo4 = *reinterpret_cast<const float4*>(b_o + 4 * cb);
#pragma unroll
    for (int p = 0; p < 8; ++p) {
        float s = (acc[p].x + acc[p].y) + (acc[p].z + acc[p].w);
        float q = (acc[p].x * acc[p].x + acc[p].y * acc[p].y)
                + (acc[p].z * acc[p].z + acc[p].w * acc[p].w);
        for (int off = 32; off; off >>= 1) {
            s += __shfl_xor(s, off);
            q += __shfl_xor(q, off);
        }
        const float mu  = s * (1.0f / 256.0f);
        const float var = q * (1.0f / 256.0f) - mu * mu;
        const float inv = rsqrtf(var + 1e-5f);
        float4 o;
        o.x = (acc[p].x - mu) * inv * go4.x + bo4.x;
        o.y = (acc[p].y - mu) * inv * go4.y + bo4.y;
        o.z = (acc[p].z - mu) * inv * go4.z + bo4.z;
        o.w = (acc[p].w - mu) * inv * go4.w + bo4.w;
        *reinterpret_cast<float4*>(out + base + (size_t)(8 * wv + p) * 256 + 4 * cb) = o;
    }
}

extern "C" void kernel_launch(void* const* d_in, const int* in_sizes, int n_in,
                              void* d_out, int out_size, void* d_ws, size_t ws_size,
                              hipStream_t stream) {
    const float* x   = (const float*)d_in[0];
    const float* g_m = (const float*)d_in[1];
    const float* b_m = (const float*)d_in[2];
    const float* g_s = (const float*)d_in[3];
    const float* b_s = (const float*)d_in[4];
    const float* W1  = (const float*)d_in[5];
    const float* b1  = (const float*)d_in[6];
    const float* W2  = (const float*)d_in[7];
    const float* b2  = (const float*)d_in[8];
    const float* g_o = (const float*)d_in[9];
    const float* b_o = (const float*)d_in[10];
    float* out = (float*)d_out;

    feat_kernel<<<NBATCH, 512, 0, stream>>>(x, g_m, b_m, g_s, b_s, out);
    mlp_kernel<<<NBLK_B, 256, 0, stream>>>(W1, b1, W2, b2, g_o, b_o, out);
}